// Round 1
// baseline (105.146 us; speedup 1.0000x reference)
//
#include <hip/hip_runtime.h>
#include <math.h>

// BFS_Refine: the reference returns (trace[64], gates[2]) only.
//
// Dead-code analysis of the reference:
//   * gates[i] = sigmoid(alpha_i)                       (depends only on alpha)
//   * trace depends only on the color-refinement chain, which is closed-form:
//       col starts all-zero -> counts[0]=N>1 -> cid=0 -> mask=ALL -> col:=1
//       layer0: sig_mean[1] = E/N   (every edge contributes one_hot(col=1) once)
//       col all-1 -> counts[1]=N>1 -> cid=1 -> mask=ALL -> col:=2
//       layer1: sig_mean[2] = E/N
//       trace = ((0 + s0)/2 + s1)/2  ->  trace[1] = E/(4N), trace[2] = E/(2N)
//   * The GIN MLP (agg/y/h/xc) never reaches the returned values.
//
// So the kernel reads the two alpha scalars, takes E and N from in_sizes
// (host side), and writes 66 floats. Exact in fp32 (E/N = 16, powers of two).

__global__ void BFS_Refine_64682207478385_kernel(const float* __restrict__ alpha0,
                                                 const float* __restrict__ alpha1,
                                                 float e_over_n,
                                                 float* __restrict__ out) {
    const int i = threadIdx.x;
    if (i < 64) {
        // trace
        float v = 0.0f;
        if (i == 1) v = e_over_n * 0.25f;   // (E/N)/4
        if (i == 2) v = e_over_n * 0.5f;    // (E/N)/2
        out[i] = v;
    } else if (i == 64) {
        // gate 0 = sigmoid(alpha_0)
        out[64] = 1.0f / (1.0f + __expf(-alpha0[0]));
    } else if (i == 65) {
        // gate 1 = sigmoid(alpha_1)
        out[65] = 1.0f / (1.0f + __expf(-alpha1[0]));
    }
}

extern "C" void kernel_launch(void* const* d_in, const int* in_sizes, int n_in,
                              void* d_out, int out_size, void* d_ws, size_t ws_size,
                              hipStream_t stream) {
    // setup_inputs() order:
    //  0: x [N,127]          1: edge_index [2,E]
    //  2: W1_0  3: b1_0  4: W2_0  5: b2_0  6: alpha_0
    //  7: W1_1  8: b1_1  9: W2_1 10: b2_1 11: alpha_1
    const float* alpha0 = (const float*)d_in[6];
    const float* alpha1 = (const float*)d_in[11];

    const double E = (double)(in_sizes[1] / 2);     // edge_index has 2*E elems
    const double N = (double)(in_sizes[0] / 127);   // x has N*127 elems
    const float e_over_n = (float)(E / N);          // 16.0 exactly here

    float* out = (float*)d_out;                     // 66 fp32: trace[64] ++ gates[2]

    BFS_Refine_64682207478385_kernel<<<1, 128, 0, stream>>>(alpha0, alpha1, e_over_n, out);
}